// Round 6
// baseline (466.759 us; speedup 1.0000x reference)
//
#include <hip/hip_runtime.h>
#include <cstdint>
#include <cstddef>

// Problem constants
#define BB 2
#define HB 16
#define LL 2048
#define DD 128
#define MM 4096   // B*L
#define KK 2048   // DIM
#define N1 6144   // 3*DIM
#define N2 2048   // DIM
#define BHLD (BB*HB*LL*DD)  // 8388608 elements per q/k/v section

typedef unsigned short u16;
typedef __bf16 bf16x8 __attribute__((ext_vector_type(8)));   // 4 VGPRs: mfma 16x16x32 A/B operand
typedef short  s16x4  __attribute__((ext_vector_type(4)));   // 2 VGPRs: mfma 16x16x16 (_1k) A/B operand
typedef float  f32x4  __attribute__((ext_vector_type(4)));

typedef __attribute__((address_space(1))) void* as1_ptr;
typedef __attribute__((address_space(3))) void* as3_ptr;

// async global->LDS, 16B per lane; LDS dest = wave-uniform base + lane*16 [m97/m104]
__device__ __forceinline__ void gload16(const void* g, void* l) {
  __builtin_amdgcn_global_load_lds((as1_ptr)g, (as3_ptr)l, 16, 0, 0);
}

__device__ __forceinline__ float bf2f(u16 u) {
  union { unsigned v; float f; } c; c.v = ((unsigned)u) << 16; return c.f;
}
__device__ __forceinline__ u16 f2bf(float f) {  // round-to-nearest-even
  unsigned u = __builtin_bit_cast(unsigned, f);
  return (u16)((u + 0x7FFFu + ((u >> 16) & 1u)) >> 16);
}

// ---------------- prep kernels ----------------

__global__ __launch_bounds__(256) void f32_to_bf16_vec(
    const float* __restrict__ in, u16* __restrict__ out, int n4) {
  int i = blockIdx.x * 256 + threadIdx.x;
  if (i >= n4) return;
  float4 v = ((const float4*)in)[i];
  ushort4 o;
  o.x = f2bf(v.x); o.y = f2bf(v.y); o.z = f2bf(v.z); o.w = f2bf(v.w);
  ((ushort4*)out)[i] = o;
}

// in: fp32 [R][C] row-major  ->  out: bf16 [C][R]
__global__ __launch_bounds__(256) void transpose_f32_bf16(
    const float* __restrict__ in, u16* __restrict__ out, int R, int C) {
  __shared__ float t[32][33];
  int c0 = blockIdx.x * 32, r0 = blockIdx.y * 32;
  int tx = threadIdx.x & 31, ty = threadIdx.x >> 5;  // 8 rows per pass
#pragma unroll
  for (int i = ty; i < 32; i += 8)
    t[i][tx] = in[(size_t)(r0 + i) * C + c0 + tx];
  __syncthreads();
#pragma unroll
  for (int i = ty; i < 32; i += 8)
    out[(size_t)(c0 + i) * R + r0 + tx] = f2bf(t[tx][i]);
}

// ---------------- GEMM (A [M][K] bf16, Bt [N][K] bf16) ----------------
// m97 pattern + BK=64 + XOR chunk swizzle:
//   - global_load_lds width=16 staging, single-buffer, 2 barriers per 64-wide K-iter
//   - tile rows stored as 8 chunks of 8 elems; logical chunk Lc lives at physical
//     chunk Lc^(r&7). Swizzle applied on the global SOURCE address (same 128B
//     segment, permuted) so coalescing is preserved; frag reads then hit all 8
//     bank-groups with 2 lanes each -> conflict-free [m136, verified round 5: 0 conflicts].
// MODE 0: epilogue scatters qkv: q,k as [B][H][L][D], v as [B][H][D][L] (bf16)
// MODE 1: plain fp32 row-major store [M][N]
template<int MODE>
__global__ __launch_bounds__(256) void gemm_bt(
    const u16* __restrict__ A, const u16* __restrict__ Bt,
    const float* __restrict__ bias, void* __restrict__ Cout,
    int Msz, int Nsz, int Ksz)
{
  __shared__ __align__(16) u16 As[128*64];   // 16 KB
  __shared__ __align__(16) u16 Bs[128*64];   // 16 KB
  const int tid  = threadIdx.x;
  const int lane = tid & 63;
  const int wid  = tid >> 6;
  const int l15  = lane & 15, quad = lane >> 4;
  const int m0 = blockIdx.y * 128, n0 = blockIdx.x * 128;
  const int wm = (wid >> 1) * 64, wn = (wid & 1) * 64;

  f32x4 acc[4][4] = {};

  for (int ks = 0; ks < Ksz; ks += 64) {
    __syncthreads();
    // staging: 1024 16B-slots per tile; slot s -> row s>>3, chunk s&7 (swizzled)
#pragma unroll
    for (int j = 0; j < 4; j++) {
      const int s = (wid*4 + j)*64 + lane;
      const int row = s >> 3, pc = (s & 7) ^ (row & 7);
      gload16(&A [(size_t)(m0 + row) * Ksz + ks + pc*8], &As[(wid*4 + j)*512]);
      gload16(&Bt[(size_t)(n0 + row) * Ksz + ks + pc*8], &Bs[(wid*4 + j)*512]);
    }
    __syncthreads();
#pragma unroll
    for (int kh = 0; kh < 2; kh++) {
      bf16x8 af[4], bfr[4];
#pragma unroll
      for (int i = 0; i < 4; i++) {
        const int r = wm + i*16 + l15;
        af[i]  = *(const bf16x8*)&As[r*64 + (((kh*4 + quad) ^ (r & 7)))*8];
      }
#pragma unroll
      for (int i = 0; i < 4; i++) {
        const int r = wn + i*16 + l15;
        bfr[i] = *(const bf16x8*)&Bs[r*64 + (((kh*4 + quad) ^ (r & 7)))*8];
      }
#pragma unroll
      for (int i = 0; i < 4; i++)
#pragma unroll
        for (int j = 0; j < 4; j++)
          acc[i][j] = __builtin_amdgcn_mfma_f32_16x16x32_bf16(af[i], bfr[j], acc[i][j], 0, 0, 0);
    }
  }

  // C/D layout: row = quad*4+reg (m), col = lane&15 (n)  [verified m89/m91]
#pragma unroll
  for (int i = 0; i < 4; i++) {
#pragma unroll
    for (int j = 0; j < 4; j++) {
      const int col = n0 + wn + j*16 + l15;
      const float bv = bias[col];
#pragma unroll
      for (int r = 0; r < 4; r++) {
        const int row = m0 + wm + i*16 + quad*4 + r;
        float v = acc[i][j][r] + bv;
        if (MODE == 0) {
          u16* qkv = (u16*)Cout;
          int t = col >> 11, hd = col & 2047, h = hd >> 7, d = hd & 127;
          int b = row >> 11, l = row & (LL - 1);
          size_t dst;
          if (t < 2) dst = (size_t)t * BHLD + (((size_t)(b*HB + h)) * LL + l) * DD + d;
          else       dst = (size_t)2 * BHLD + (((size_t)(b*HB + h)) * DD + d) * LL + l;
          qkv[dst] = f2bf(v);
        } else {
          ((float*)Cout)[(size_t)row * Nsz + col] = v;
        }
      }
    }
  }
}

// ---------------- fused RMSNorm + RoPE on q,k (in place, bf16) ----------------
// one wave per (b,h,l) row of 128; lane owns pair p = lane (D/2 = 64 pairs)
// q is additionally pre-scaled by 1/sqrt(D) so attn scores come out of MFMA ready.
__global__ __launch_bounds__(256) void norm_rope(
    u16* __restrict__ qkv, const float* __restrict__ pe,
    const float* __restrict__ qsc, const float* __restrict__ ksc)
{
  const int wid = threadIdx.x >> 6, lane = threadIdx.x & 63;
  const int r = blockIdx.x * 4 + wid;      // [0, B*H*L)
  const int l = r & (LL - 1);
  const float4 p4 = *(const float4*)&pe[((size_t)l * 64 + lane) * 4]; // [[c,-s],[s,c]] row-major
#pragma unroll
  for (int t = 0; t < 2; t++) {
    u16* base = qkv + (size_t)t * BHLD + (size_t)r * DD + lane * 2;
    const float* sc = t ? ksc : qsc;
    ushort2 xx = *(const ushort2*)base;
    float x0 = bf2f(xx.x), x1 = bf2f(xx.y);
    float ss = x0*x0 + x1*x1;
#pragma unroll
    for (int m = 1; m < 64; m <<= 1) ss += __shfl_xor(ss, m, 64);
    float rr = rsqrtf(ss * (1.0f/128.0f) + 1e-6f);
    if (t == 0) rr *= 0.08838834764831845f;  // fold 1/sqrt(128) into q
    float y0 = x0 * rr * sc[lane*2], y1 = x1 * rr * sc[lane*2 + 1];
    ushort2 oo;
    oo.x = f2bf(p4.x * y0 + p4.y * y1);
    oo.y = f2bf(p4.z * y0 + p4.w * y1);
    *(ushort2*)base = oo;
  }
}

// ---------------- flash attention v4 ----------------
// Fixed-shift softmax (|s|<=sqrt(128) since q,k RMS-normed): no running max/rescale.
// BKT=32: 32 KB LDS (2x(8K+8V) dbuf) -> 3 blocks/CU via launch_bounds(256,3)
// (was 64 KB / 2 blocks/CU: latency-bound at 2 waves/SIMD).
// Async global_load_lds double-buffer, 1 barrier per iter:
//   barrier (drains cur) -> issue async loads for tile i+1 into cur^1 -> compute cur.
// Bank conflicts broken by source-side XOR chunk swizzle (K: 16-chunk rows, c^(r&7);
// V^T: 4-chunk rows, c^(r&3)).
// S^T = K.Q^T (16x16x32) -> P lands in A-operand layout for PV (16x16x16). O in regs.
#define BKT 32
__global__ __launch_bounds__(256, 3) void attn(
    const u16* __restrict__ qkv, u16* __restrict__ Oout)
{
  __shared__ __align__(16) u16 Ksh[2][BKT * DD];   // 2 x 8 KB
  __shared__ __align__(16) u16 Vsh[2][DD * BKT];   // 2 x 8 KB

  const int bh = blockIdx.x >> 4, qt = blockIdx.x & 15;
  const int wid = threadIdx.x >> 6, lane = threadIdx.x & 63;
  const int l15 = lane & 15, quad = lane >> 4;
  const int q0 = qt * 128 + wid * 32;
  const u16* qp = qkv + (size_t)bh * LL * DD;
  const u16* kp = qkv + (size_t)BHLD + (size_t)bh * LL * DD;
  const u16* vp = qkv + (size_t)2 * BHLD + (size_t)bh * DD * LL;  // V^T [D][L]

  // Q fragments, held for entire kernel: 2 qfrags x 4 d-frags
  bf16x8 qb[2][4];
#pragma unroll
  for (int qf = 0; qf < 2; qf++)
#pragma unroll
    for (int f = 0; f < 4; f++)
      qb[qf][f] = *(const bf16x8*)&qp[(size_t)(q0 + qf*16 + l15) * DD + f*32 + quad*8];

  float l_acc[2] = {0.f, 0.f};
  f32x4 oacc[2][8] = {};

  // async stage of one K/V tile into buffer `buf` (wave issues 2+2 instrs)
  auto stage = [&](int buf, int k0) {
#pragma unroll
    for (int j = 0; j < 2; j++) {
      const int s = (wid*2 + j)*64 + lane;
      { // K: 32 rows x 16 chunks of 16B
        const int r = s >> 4, c = s & 15;
        const int lc = (c & 8) | ((c & 7) ^ (r & 7));
        gload16(&kp[(size_t)(k0 + r) * DD + lc*8], &Ksh[buf][(wid*2 + j)*512]);
      }
      { // V^T: 128 rows x 4 chunks of 16B
        const int r = s >> 2, c = s & 3;
        const int lc = c ^ (r & 3);
        gload16(&vp[(size_t)r * LL + k0 + lc*8], &Vsh[buf][(wid*2 + j)*512]);
      }
    }
  };

  stage(0, 0);
  int cur = 0;

  for (int k0 = 0; k0 < LL; k0 += BKT) {
    __syncthreads();                       // drains buf[cur] loads; frees buf[cur^1]
    if (k0 + BKT < LL) stage(cur ^ 1, k0 + BKT);

    // S^T = K . Q^T : m = 32 keys (2 tiles), n = 16 q per qfrag
    f32x4 s[2][2] = {};
#pragma unroll
    for (int f = 0; f < 4; f++) {
      bf16x8 kf[2];
#pragma unroll
      for (int mt = 0; mt < 2; mt++) {
        const int rr = mt*16 + l15;
        const int Lc = f*4 + quad;
        const int pc = (Lc & 8) | ((Lc & 7) ^ (rr & 7));
        kf[mt] = *(const bf16x8*)&Ksh[cur][rr*DD + pc*8];
      }
#pragma unroll
      for (int qf = 0; qf < 2; qf++)
#pragma unroll
        for (int mt = 0; mt < 2; mt++)
          s[qf][mt] = __builtin_amdgcn_mfma_f32_16x16x32_bf16(kf[mt], qb[qf][f], s[qf][mt], 0, 0, 0);
    }

    // exp(s - 12), accumulate l, pack P to bf16 A-frags
    s16x4 pa[2][2];
#pragma unroll
    for (int qf = 0; qf < 2; qf++) {
#pragma unroll
      for (int mt = 0; mt < 2; mt++) {
        float p0 = __expf(s[qf][mt][0] - 12.f);
        float p1 = __expf(s[qf][mt][1] - 12.f);
        float p2 = __expf(s[qf][mt][2] - 12.f);
        float p3 = __expf(s[qf][mt][3] - 12.f);
        l_acc[qf] += (p0 + p1) + (p2 + p3);
        pa[qf][mt][0] = (short)f2bf(p0); pa[qf][mt][1] = (short)f2bf(p1);
        pa[qf][mt][2] = (short)f2bf(p2); pa[qf][mt][3] = (short)f2bf(p3);
      }
    }

    // O += P . V : per k-chunk t (16 keys), 8 d-tiles, both qfrags share vb
#pragma unroll
    for (int t = 0; t < 2; t++) {
      s16x4 vb[8];
#pragma unroll
      for (int c = 0; c < 8; c++) {
        const int rv = c*16 + l15;
        const int Lc = t*2 + (quad >> 1);
        const int pc = Lc ^ (rv & 3);
        vb[c] = *(const s16x4*)&Vsh[cur][rv*BKT + pc*8 + (quad & 1)*4];
      }
#pragma unroll
      for (int qf = 0; qf < 2; qf++)
#pragma unroll
        for (int c = 0; c < 8; c++)
          oacc[qf][c] = __builtin_amdgcn_mfma_f32_16x16x16bf16_1k(pa[qf][t], vb[c], oacc[qf][c], 0, 0, 0);
    }
    cur ^= 1;
  }

  // final: reduce l across the 4 quad-replicas, normalize, store
#pragma unroll
  for (int qf = 0; qf < 2; qf++) {
    l_acc[qf] += __shfl_xor(l_acc[qf], 16, 64);
    l_acc[qf] += __shfl_xor(l_acc[qf], 32, 64);
  }
  const int b = bh >> 4, h = bh & 15;
#pragma unroll
  for (int qf = 0; qf < 2; qf++) {
    float lr[4];
#pragma unroll
    for (int r = 0; r < 4; r++)
      lr[r] = 1.0f / __shfl(l_acc[qf], (quad << 4) | (quad*4 + r), 64);
#pragma unroll
    for (int c = 0; c < 8; c++)
#pragma unroll
      for (int r = 0; r < 4; r++) {
        int qrow = q0 + qf*16 + quad*4 + r;
        Oout[((size_t)(b*LL + qrow)) * N2 + h*DD + c*16 + l15] = f2bf(oacc[qf][c][r] * lr[r]);
      }
  }
}

// ---------------- launch ----------------

extern "C" void kernel_launch(void* const* d_in, const int* in_sizes, int n_in,
                              void* d_out, int out_size, void* d_ws, size_t ws_size,
                              hipStream_t stream) {
  const float* x       = (const float*)d_in[0];
  const float* pe      = (const float*)d_in[1];
  const float* qkv_w   = (const float*)d_in[2];
  const float* qkv_b   = (const float*)d_in[3];
  const float* q_scale = (const float*)d_in[4];
  const float* k_scale = (const float*)d_in[5];
  const float* proj_w  = (const float*)d_in[6];
  const float* proj_b  = (const float*)d_in[7];

  // workspace layout (bytes): needs 112 MB
  char* ws = (char*)d_ws;
  u16* xb   = (u16*)(ws + 0);           // [4096][2048] bf16   : 16 MB
  u16* w1t  = (u16*)(ws + 16777216);    // [6144][2048] bf16   : 24 MB
  u16* w2t  = (u16*)(ws + 41943040);    // [2048][2048] bf16   :  8 MB
  u16* qkv  = (u16*)(ws + 50331648);    // q,k [B,H,L,D], v [B,H,D,L] bf16 : 48 MB
  u16* attO = (u16*)(ws + 100663296);   // [4096][2048] bf16   : 16 MB

  f32_to_bf16_vec<<<(MM*KK/4)/256, 256, 0, stream>>>(x, xb, MM*KK/4);
  transpose_f32_bf16<<<dim3(N1/32, KK/32), 256, 0, stream>>>(qkv_w, w1t, KK, N1);
  transpose_f32_bf16<<<dim3(N2/32, KK/32), 256, 0, stream>>>(proj_w, w2t, KK, N2);
  gemm_bt<0><<<dim3(N1/128, MM/128), 256, 0, stream>>>(xb, w1t, qkv_b, (void*)qkv, MM, N1, KK);
  norm_rope<<<(BB*HB*LL)/4, 256, 0, stream>>>(qkv, pe, q_scale, k_scale);
  attn<<<BB*HB*(LL/128), 256, 0, stream>>>(qkv, attO);
  gemm_bt<1><<<dim3(N2/128, MM/128), 256, 0, stream>>>(attO, w2t, proj_b, d_out, MM, N2, KK);
}

// Round 7
// 441.980 us; speedup vs baseline: 1.0561x; 1.0561x over previous
//
#include <hip/hip_runtime.h>
#include <cstdint>
#include <cstddef>

// Problem constants
#define BB 2
#define HB 16
#define LL 2048
#define DD 128
#define MM 4096   // B*L
#define KK 2048   // DIM
#define N1 6144   // 3*DIM
#define N2 2048   // DIM
#define BHLD (BB*HB*LL*DD)  // 8388608 elements per q/k/v section

typedef unsigned short u16;
typedef __bf16 bf16x8 __attribute__((ext_vector_type(8)));   // 4 VGPRs: mfma 16x16x32 A/B operand
typedef short  s16x4  __attribute__((ext_vector_type(4)));   // 2 VGPRs: mfma 16x16x16 (_1k) A/B operand
typedef float  f32x4  __attribute__((ext_vector_type(4)));

typedef __attribute__((address_space(1))) void* as1_ptr;
typedef __attribute__((address_space(3))) void* as3_ptr;

// async global->LDS, 16B per lane; LDS dest = wave-uniform base + lane*16 [m97/m104]
__device__ __forceinline__ void gload16(const void* g, void* l) {
  __builtin_amdgcn_global_load_lds((as1_ptr)g, (as3_ptr)l, 16, 0, 0);
}

__device__ __forceinline__ float bf2f(u16 u) {
  union { unsigned v; float f; } c; c.v = ((unsigned)u) << 16; return c.f;
}
__device__ __forceinline__ u16 f2bf(float f) {  // round-to-nearest-even
  unsigned u = __builtin_bit_cast(unsigned, f);
  return (u16)((u + 0x7FFFu + ((u >> 16) & 1u)) >> 16);
}

// ---------------- prep kernels ----------------

__global__ __launch_bounds__(256) void f32_to_bf16_vec(
    const float* __restrict__ in, u16* __restrict__ out, int n4) {
  int i = blockIdx.x * 256 + threadIdx.x;
  if (i >= n4) return;
  float4 v = ((const float4*)in)[i];
  ushort4 o;
  o.x = f2bf(v.x); o.y = f2bf(v.y); o.z = f2bf(v.z); o.w = f2bf(v.w);
  ((ushort4*)out)[i] = o;
}

// in: fp32 [R][C] row-major  ->  out: bf16 [C][R]
__global__ __launch_bounds__(256) void transpose_f32_bf16(
    const float* __restrict__ in, u16* __restrict__ out, int R, int C) {
  __shared__ float t[32][33];
  int c0 = blockIdx.x * 32, r0 = blockIdx.y * 32;
  int tx = threadIdx.x & 31, ty = threadIdx.x >> 5;  // 8 rows per pass
#pragma unroll
  for (int i = ty; i < 32; i += 8)
    t[i][tx] = in[(size_t)(r0 + i) * C + c0 + tx];
  __syncthreads();
#pragma unroll
  for (int i = ty; i < 32; i += 8)
    out[(size_t)(c0 + i) * R + r0 + tx] = f2bf(t[tx][i]);
}

// ---------------- GEMM (A [M][K] bf16, Bt [N][K] bf16) ----------------
// m97 pattern + BK=64 + XOR chunk swizzle (round 5: 0 bank conflicts, 760 TF plateau).
// MODE 0: epilogue scatters qkv: q,k as [B][H][L][D], v as [B][H][D][L] (bf16)
// MODE 1: plain fp32 row-major store [M][N]
template<int MODE>
__global__ __launch_bounds__(256) void gemm_bt(
    const u16* __restrict__ A, const u16* __restrict__ Bt,
    const float* __restrict__ bias, void* __restrict__ Cout,
    int Msz, int Nsz, int Ksz)
{
  __shared__ __align__(16) u16 As[128*64];   // 16 KB
  __shared__ __align__(16) u16 Bs[128*64];   // 16 KB
  const int tid  = threadIdx.x;
  const int lane = tid & 63;
  const int wid  = tid >> 6;
  const int l15  = lane & 15, quad = lane >> 4;
  const int m0 = blockIdx.y * 128, n0 = blockIdx.x * 128;
  const int wm = (wid >> 1) * 64, wn = (wid & 1) * 64;

  f32x4 acc[4][4] = {};

  for (int ks = 0; ks < Ksz; ks += 64) {
    __syncthreads();
    // staging: 1024 16B-slots per tile; slot s -> row s>>3, chunk s&7 (swizzled)
#pragma unroll
    for (int j = 0; j < 4; j++) {
      const int s = (wid*4 + j)*64 + lane;
      const int row = s >> 3, pc = (s & 7) ^ (row & 7);
      gload16(&A [(size_t)(m0 + row) * Ksz + ks + pc*8], &As[(wid*4 + j)*512]);
      gload16(&Bt[(size_t)(n0 + row) * Ksz + ks + pc*8], &Bs[(wid*4 + j)*512]);
    }
    __syncthreads();
#pragma unroll
    for (int kh = 0; kh < 2; kh++) {
      bf16x8 af[4], bfr[4];
#pragma unroll
      for (int i = 0; i < 4; i++) {
        const int r = wm + i*16 + l15;
        af[i]  = *(const bf16x8*)&As[r*64 + (((kh*4 + quad) ^ (r & 7)))*8];
      }
#pragma unroll
      for (int i = 0; i < 4; i++) {
        const int r = wn + i*16 + l15;
        bfr[i] = *(const bf16x8*)&Bs[r*64 + (((kh*4 + quad) ^ (r & 7)))*8];
      }
#pragma unroll
      for (int i = 0; i < 4; i++)
#pragma unroll
        for (int j = 0; j < 4; j++)
          acc[i][j] = __builtin_amdgcn_mfma_f32_16x16x32_bf16(af[i], bfr[j], acc[i][j], 0, 0, 0);
    }
  }

  // C/D layout: row = quad*4+reg (m), col = lane&15 (n)  [verified m89/m91]
#pragma unroll
  for (int i = 0; i < 4; i++) {
#pragma unroll
    for (int j = 0; j < 4; j++) {
      const int col = n0 + wn + j*16 + l15;
      const float bv = bias[col];
#pragma unroll
      for (int r = 0; r < 4; r++) {
        const int row = m0 + wm + i*16 + quad*4 + r;
        float v = acc[i][j][r] + bv;
        if (MODE == 0) {
          u16* qkv = (u16*)Cout;
          int t = col >> 11, hd = col & 2047, h = hd >> 7, d = hd & 127;
          int b = row >> 11, l = row & (LL - 1);
          size_t dst;
          if (t < 2) dst = (size_t)t * BHLD + (((size_t)(b*HB + h)) * LL + l) * DD + d;
          else       dst = (size_t)2 * BHLD + (((size_t)(b*HB + h)) * DD + d) * LL + l;
          qkv[dst] = f2bf(v);
        } else {
          ((float*)Cout)[(size_t)row * Nsz + col] = v;
        }
      }
    }
  }
}

// ---------------- fused RMSNorm + RoPE on q,k (in place, bf16) ----------------
// one wave per (b,h,l) row of 128; lane owns pair p = lane (D/2 = 64 pairs)
// q is additionally pre-scaled by 1/sqrt(D) so attn scores come out of MFMA ready.
__global__ __launch_bounds__(256) void norm_rope(
    u16* __restrict__ qkv, const float* __restrict__ pe,
    const float* __restrict__ qsc, const float* __restrict__ ksc)
{
  const int wid = threadIdx.x >> 6, lane = threadIdx.x & 63;
  const int r = blockIdx.x * 4 + wid;      // [0, B*H*L)
  const int l = r & (LL - 1);
  const float4 p4 = *(const float4*)&pe[((size_t)l * 64 + lane) * 4]; // [[c,-s],[s,c]] row-major
#pragma unroll
  for (int t = 0; t < 2; t++) {
    u16* base = qkv + (size_t)t * BHLD + (size_t)r * DD + lane * 2;
    const float* sc = t ? ksc : qsc;
    ushort2 xx = *(const ushort2*)base;
    float x0 = bf2f(xx.x), x1 = bf2f(xx.y);
    float ss = x0*x0 + x1*x1;
#pragma unroll
    for (int m = 1; m < 64; m <<= 1) ss += __shfl_xor(ss, m, 64);
    float rr = rsqrtf(ss * (1.0f/128.0f) + 1e-6f);
    if (t == 0) rr *= 0.08838834764831845f;  // fold 1/sqrt(128) into q
    float y0 = x0 * rr * sc[lane*2], y1 = x1 * rr * sc[lane*2 + 1];
    ushort2 oo;
    oo.x = f2bf(p4.x * y0 + p4.y * y1);
    oo.y = f2bf(p4.z * y0 + p4.w * y1);
    *(ushort2*)base = oo;
  }
}

// ---------------- flash attention v5 ----------------
// Fixed-shift softmax (|s|<=sqrt(128) since q,k RMS-normed): no running max/rescale.
// BKT=64, 64 KB LDS dbuf, 2 blocks/CU.
// KEY FIX vs v3/v4: ALL ds_reads of the current tile are issued BEFORE stage() of
// the next tile. global_load_lds writes LDS; the compiler cannot disambiguate
// buf[cur] from buf[cur^1] and orders any later ds_read after the async loads
// (vmcnt drain) -> v3/v4 exposed full load latency every iteration. With reads
// hoisted, staged loads get exp+PV+next-QK (~1000 cyc) of cover before the barrier.
// XCD swizzle: bh = blockIdx.x&31 -> all 16 q-tiles of a head on one XCD
// (round-robin dispatch), 4 heads/XCD ~= 4MB K+V = L2-resident.
// S^T = K.Q^T (16x16x32) -> P lands in A-operand layout for PV (16x16x16). O in regs.
#define BKT 64
__global__ __launch_bounds__(256, 2) void attn(
    const u16* __restrict__ qkv, u16* __restrict__ Oout)
{
  __shared__ __align__(16) u16 Ksh[2][BKT * DD];   // 2 x 16 KB
  __shared__ __align__(16) u16 Vsh[2][DD * BKT];   // 2 x 16 KB

  const int bh = blockIdx.x & 31, qt = blockIdx.x >> 5;   // XCD-locality swizzle
  const int wid = threadIdx.x >> 6, lane = threadIdx.x & 63;
  const int l15 = lane & 15, quad = lane >> 4;
  const int q0 = qt * 128 + wid * 32;
  const u16* qp = qkv + (size_t)bh * LL * DD;
  const u16* kp = qkv + (size_t)BHLD + (size_t)bh * LL * DD;
  const u16* vp = qkv + (size_t)2 * BHLD + (size_t)bh * DD * LL;  // V^T [D][L]

  // Q fragments, held for entire kernel: 2 qfrags x 4 d-frags
  bf16x8 qb[2][4];
#pragma unroll
  for (int qf = 0; qf < 2; qf++)
#pragma unroll
    for (int f = 0; f < 4; f++)
      qb[qf][f] = *(const bf16x8*)&qp[(size_t)(q0 + qf*16 + l15) * DD + f*32 + quad*8];

  float l_acc[2] = {0.f, 0.f};
  f32x4 oacc[2][8] = {};

  // async stage of one K/V tile into buffer `buf` (wave issues 4+4 instrs)
  auto stage = [&](int buf, int k0) {
#pragma unroll
    for (int j = 0; j < 4; j++) {
      const int s = (wid*4 + j)*64 + lane;
      { // K: 64 rows x 16 chunks of 16B
        const int r = s >> 4, c = s & 15;
        const int lc = (c & 8) | ((c & 7) ^ (r & 7));
        gload16(&kp[(size_t)(k0 + r) * DD + lc*8], &Ksh[buf][(wid*4 + j)*512]);
      }
      { // V^T: 128 rows x 8 chunks of 16B
        const int r = s >> 3, c = s & 7;
        const int lc = c ^ (r & 7);
        gload16(&vp[(size_t)r * LL + k0 + lc*8], &Vsh[buf][(wid*4 + j)*512]);
      }
    }
  };

  stage(0, 0);
  int cur = 0;

  for (int k0 = 0; k0 < LL; k0 += BKT) {
    __syncthreads();                       // drains buf[cur] loads; frees buf[cur^1]

    // --- phase 1: QK (all ds_reads from buf[cur], interleaved with MFMAs) ---
    f32x4 s[2][4] = {};
#pragma unroll
    for (int f = 0; f < 4; f++) {
      bf16x8 kf[4];
#pragma unroll
      for (int mt = 0; mt < 4; mt++) {
        const int rr = mt*16 + l15;
        const int Lc = f*4 + quad;
        const int pc = (Lc & 8) | ((Lc & 7) ^ (rr & 7));
        kf[mt] = *(const bf16x8*)&Ksh[cur][rr*DD + pc*8];
      }
#pragma unroll
      for (int qf = 0; qf < 2; qf++)
#pragma unroll
        for (int mt = 0; mt < 4; mt++)
          s[qf][mt] = __builtin_amdgcn_mfma_f32_16x16x32_bf16(kf[mt], qb[qf][f], s[qf][mt], 0, 0, 0);
    }

    // --- phase 2: read ALL V frags for this tile (last LDS reads of the iter) ---
    s16x4 vb[4][8];
#pragma unroll
    for (int t = 0; t < 4; t++)
#pragma unroll
      for (int c = 0; c < 8; c++) {
        const int rv = c*16 + l15;
        const int pc = (t*2 + (quad >> 1)) ^ (l15 & 7);
        vb[t][c] = *(const s16x4*)&Vsh[cur][rv*BKT + pc*8 + (quad & 1)*4];
      }

    // --- phase 3: NOW issue next tile's async loads (no ds_read follows) ---
    if (k0 + BKT < LL) stage(cur ^ 1, k0 + BKT);

    // --- phase 4: exp(s - 12), accumulate l, pack P to bf16 A-frags ---
    s16x4 pa[2][4];
#pragma unroll
    for (int qf = 0; qf < 2; qf++) {
#pragma unroll
      for (int mt = 0; mt < 4; mt++) {
        float p0 = __expf(s[qf][mt][0] - 12.f);
        float p1 = __expf(s[qf][mt][1] - 12.f);
        float p2 = __expf(s[qf][mt][2] - 12.f);
        float p3 = __expf(s[qf][mt][3] - 12.f);
        l_acc[qf] += (p0 + p1) + (p2 + p3);
        pa[qf][mt][0] = (short)f2bf(p0); pa[qf][mt][1] = (short)f2bf(p1);
        pa[qf][mt][2] = (short)f2bf(p2); pa[qf][mt][3] = (short)f2bf(p3);
      }
    }

    // --- phase 5: O += P . V ---
#pragma unroll
    for (int t = 0; t < 4; t++)
#pragma unroll
      for (int qf = 0; qf < 2; qf++)
#pragma unroll
        for (int c = 0; c < 8; c++)
          oacc[qf][c] = __builtin_amdgcn_mfma_f32_16x16x16bf16_1k(pa[qf][t], vb[t][c], oacc[qf][c], 0, 0, 0);

    cur ^= 1;
  }

  // final: reduce l across the 4 quad-replicas, normalize, store
#pragma unroll
  for (int qf = 0; qf < 2; qf++) {
    l_acc[qf] += __shfl_xor(l_acc[qf], 16, 64);
    l_acc[qf] += __shfl_xor(l_acc[qf], 32, 64);
  }
  const int b = bh >> 4, h = bh & 15;
#pragma unroll
  for (int qf = 0; qf < 2; qf++) {
    float lr[4];
#pragma unroll
    for (int r = 0; r < 4; r++)
      lr[r] = 1.0f / __shfl(l_acc[qf], (quad << 4) | (quad*4 + r), 64);
#pragma unroll
    for (int c = 0; c < 8; c++)
#pragma unroll
      for (int r = 0; r < 4; r++) {
        int qrow = q0 + qf*16 + quad*4 + r;
        Oout[((size_t)(b*LL + qrow)) * N2 + h*DD + c*16 + l15] = f2bf(oacc[qf][c][r] * lr[r]);
      }
  }
}

// ---------------- launch ----------------

extern "C" void kernel_launch(void* const* d_in, const int* in_sizes, int n_in,
                              void* d_out, int out_size, void* d_ws, size_t ws_size,
                              hipStream_t stream) {
  const float* x       = (const float*)d_in[0];
  const float* pe      = (const float*)d_in[1];
  const float* qkv_w   = (const float*)d_in[2];
  const float* qkv_b   = (const float*)d_in[3];
  const float* q_scale = (const float*)d_in[4];
  const float* k_scale = (const float*)d_in[5];
  const float* proj_w  = (const float*)d_in[6];
  const float* proj_b  = (const float*)d_in[7];

  // workspace layout (bytes): needs 112 MB
  char* ws = (char*)d_ws;
  u16* xb   = (u16*)(ws + 0);           // [4096][2048] bf16   : 16 MB
  u16* w1t  = (u16*)(ws + 16777216);    // [6144][2048] bf16   : 24 MB
  u16* w2t  = (u16*)(ws + 41943040);    // [2048][2048] bf16   :  8 MB
  u16* qkv  = (u16*)(ws + 50331648);    // q,k [B,H,L,D], v [B,H,D,L] bf16 : 48 MB
  u16* attO = (u16*)(ws + 100663296);   // [4096][2048] bf16   : 16 MB

  f32_to_bf16_vec<<<(MM*KK/4)/256, 256, 0, stream>>>(x, xb, MM*KK/4);
  transpose_f32_bf16<<<dim3(N1/32, KK/32), 256, 0, stream>>>(qkv_w, w1t, KK, N1);
  transpose_f32_bf16<<<dim3(N2/32, KK/32), 256, 0, stream>>>(proj_w, w2t, KK, N2);
  gemm_bt<0><<<dim3(N1/128, MM/128), 256, 0, stream>>>(xb, w1t, qkv_b, (void*)qkv, MM, N1, KK);
  norm_rope<<<(BB*HB*LL)/4, 256, 0, stream>>>(qkv, pe, q_scale, k_scale);
  attn<<<BB*HB*(LL/128), 256, 0, stream>>>(qkv, attO);
  gemm_bt<1><<<dim3(N2/128, MM/128), 256, 0, stream>>>(attO, w2t, proj_b, d_out, MM, N2, KK);
}